// Round 5
// baseline (4165.012 us; speedup 1.0000x reference)
//
#include <hip/hip_runtime.h>
#include <hip/hip_bf16.h>

typedef unsigned short u16;
typedef __attribute__((ext_vector_type(8))) short bf16x8;
typedef __attribute__((ext_vector_type(4))) float f32x4;
typedef __attribute__((ext_vector_type(8))) unsigned short u16x8;
typedef __attribute__((ext_vector_type(4))) unsigned short u16x4;

__device__ __forceinline__ u16 f2bf(float v) {
    __hip_bfloat16 b = __float2bfloat16(v);
    return *reinterpret_cast<u16*>(&b);
}
__device__ __forceinline__ float bf2f(u16 u) {
    __hip_bfloat16 b;
    *reinterpret_cast<u16*>(&b) = u;
    return __bfloat162float(b);
}

// ---------------------------------------------------------------------------
// weight repack OIHW fp32 -> [oc][p*Cin+ic] bf16 (hi[,lo]) ; p = ky*KS+kx
// ---------------------------------------------------------------------------
__global__ void repack_w32(const float* __restrict__ w, u16* __restrict__ wh,
                           u16* __restrict__ wl, int Cout, int Cin, int KK) {
    int i = blockIdx.x * blockDim.x + threadIdx.x;
    int tot = Cout * Cin * KK;
    if (i >= tot) return;
    int oc = i / (Cin * KK);
    int r = i - oc * (Cin * KK);
    int p = r / Cin, ic = r - p * Cin;
    float v = w[((size_t)oc * Cin + ic) * KK + p];
    u16 h = f2bf(v);
    size_t o = (size_t)oc * (Cin * KK) + (size_t)p * Cin + ic;
    wh[o] = h;
    if (wl) wl[o] = f2bf(v - bf2f(h));
}

// weight repack OIHW (Cin=3) -> [oc][pp*4+c], pp padded to PP4 positions
__global__ void repack_w4(const float* __restrict__ w, u16* __restrict__ wh,
                          u16* __restrict__ wl, int Cout, int KK, int PP4) {
    int i = blockIdx.x * blockDim.x + threadIdx.x;
    int tot = Cout * PP4 * 4;
    if (i >= tot) return;
    int oc = i / (PP4 * 4);
    int r = i - oc * (PP4 * 4);
    int pp = r >> 2, c = r & 3;
    float v = (pp < KK && c < 3) ? w[((size_t)oc * 3 + c) * KK + pp] : 0.f;
    u16 h = f2bf(v);
    wh[i] = h;
    if (wl) wl[i] = f2bf(v - bf2f(h));
}

// ---------------------------------------------------------------------------
// extract person m: x [n,c,HW,2] chunk -> X (NCHW fp32) + Xh/Xl (NHWC-C4 bf16)
// ---------------------------------------------------------------------------
__global__ void extract_person3(const float* __restrict__ x, float* __restrict__ X,
                                u16* __restrict__ Xh, u16* __restrict__ Xl,
                                int m, int HW, size_t total) {
    size_t idx = (size_t)blockIdx.x * blockDim.x + threadIdx.x;
    if (idx >= total) return;
    int n = idx / HW;
    int p = idx - (size_t)n * HW;
    u16 h[4], l[4];
    h[3] = 0; l[3] = 0;
#pragma unroll
    for (int c = 0; c < 3; ++c) {
        float v = x[(((size_t)(n * 3 + c)) * HW + p) * 2 + m];
        X[((size_t)(n * 3 + c)) * HW + p] = v;
        u16 hh = f2bf(v);
        h[c] = hh;
        l[c] = f2bf(v - bf2f(hh));
    }
    *reinterpret_cast<u16x4*>(&Xh[((size_t)n * HW + p) * 4]) = *reinterpret_cast<u16x4*>(h);
    *reinterpret_cast<u16x4*>(&Xl[((size_t)n * HW + p) * 4]) = *reinterpret_cast<u16x4*>(l);
}

// ---------------------------------------------------------------------------
// patch-staged implicit-GEMM conv via mfma_f32_16x16x32_bf16 (NHWC acts)
//   block = 64 oc x (TY x TX) output tile; input patch staged in LDS per
//   32-channel slice; A (weights) double-buffered, 1 barrier per k-step.
// CT=32: fragment k-run = 8 channels @ one pixel (swizzled patch)
// CT=4 : fragment k-run = 2 pixels x 4 channels (C4 patch, slot-padded)
// SIN: split hi/lo (3x MFMA). MOUT: 0=bf16 NHWC, 1=split bf16 NHWC,
// 2=fp32 NCHW
// ---------------------------------------------------------------------------
template <int KS, int P, int CT, int TY, int TX, bool SIN, int MOUT>
__global__ __launch_bounds__(256) void conv_mfma_p(
    const u16* __restrict__ inh, const u16* __restrict__ inl,
    const u16* __restrict__ wh, const u16* __restrict__ wl,
    const float* __restrict__ cbias, const float* __restrict__ gam,
    const float* __restrict__ bet,
    u16* __restrict__ outh, u16* __restrict__ outl, float* __restrict__ outf,
    int Nn, int Cin, int Hin, int Win, int Cout, int Hout, int Wout,
    int Kp, int Ntiles, int tilesYX, int tilesX) {
    constexpr int KK = KS * KS;
    constexpr int SY = 2 * (TY - 1) + KS;
    constexpr int SX = 2 * (TX - 1) + KS;
    // CT4 reads padded k-slots (zero weights); pad patch rows to cover them
    constexpr int SYP = (CT == 4) ? ((KS == 5) ? SY + 2 : SY + 3) : SY;
    constexpr int PIXB = (CT == 32) ? 64 : 8;  // bytes/pixel/plane
    constexpr int PATCH_B = ((SYP * SX * PIXB + 127) & ~127);
    constexpr int NPL = SIN ? 2 : 1;

    __shared__ __align__(16) unsigned char Patch[NPL][PATCH_B];
    __shared__ __align__(16) u16 As[NPL][2][64 * 40];

    const int tid = threadIdx.x;
    // bijective XCD chunk swizzle (m204)
    {
    }
    const int nwg = gridDim.x;
    const int orig = blockIdx.x;
    const int q = nwg >> 3, r = nwg & 7, xcd = orig & 7;
    const int L = (xcd < r ? xcd * (q + 1) : r * (q + 1) + (xcd - r) * q) + (orig >> 3);
    const int bm = L / Ntiles;
    const int tile = L - bm * Ntiles;
    const int n = tile / tilesYX;
    const int r2 = tile - n * tilesYX;
    const int tyi = r2 / tilesX;
    const int ty0 = tyi * TY;
    const int tx0 = (r2 - tyi * tilesX) * TX;
    const int oc0 = bm * 64;
    const int iy0 = ty0 * 2 - P, ix0 = tx0 * 2 - P;
    const int HWin = Hin * Win, HWout = Hout * Wout;
    const size_t nbase = (size_t)n * HWin;

    const int lane = tid & 63, wv = tid >> 6;
    const int mq = (wv & 1) * 32, nq = (wv >> 1) * 32;
    const int cl = lane & 15, oct = lane >> 4;
    const int aof = mq * 40 + cl * 40 + oct * 8;
    const int sm = tid & 63, soct = tid >> 6;
    const int stg = sm * 40 + soct * 8;

    // per-lane output cols for ni=0,1
    int bbase[2];
#pragma unroll
    for (int ni = 0; ni < 2; ++ni) {
        int c = nq + ni * 16 + cl;
        int dy = c / TX, dx = c - dy * TX;
        bbase[ni] = 2 * dy * SX + 2 * dx;
    }

    f32x4 acc[2][2] = {};
    const int CS = (CT == 32) ? (Cin >> 5) : 1;
    const int PPn = (CT == 32) ? KK : (Kp >> 5);
    int step = 0;

    for (int cs = 0; cs < CS; ++cs) {
        __syncthreads();
        // ---- stage input patch for this channel slice ----
        if (CT == 32) {
            for (int j = tid; j < SY * SX * 4; j += 256) {
                int pix = j >> 2, po = j & 3;
                int sy = pix / SX, sx = pix - sy * SX;
                int iy = iy0 + sy, ix = ix0 + sx;
                bool ok = ((unsigned)iy < (unsigned)Hin) && ((unsigned)ix < (unsigned)Win);
                int bo = (pix * 64 + po * 16) ^ (((pix >> 1) & 7) << 4);
                size_t a = (nbase + (size_t)iy * Win + ix) * Cin + cs * 32 + po * 8;
                u16x8 v = {0, 0, 0, 0, 0, 0, 0, 0};
                if (ok) v = *reinterpret_cast<const u16x8*>(&inh[a]);
                *reinterpret_cast<u16x8*>(&Patch[0][bo]) = v;
                if (SIN) {
                    u16x8 w2 = {0, 0, 0, 0, 0, 0, 0, 0};
                    if (ok) w2 = *reinterpret_cast<const u16x8*>(&inl[a]);
                    *reinterpret_cast<u16x8*>(&Patch[1][bo]) = w2;
                }
            }
        } else {
            for (int j = tid; j < SYP * SX; j += 256) {
                int sy = j / SX, sx = j - sy * SX;
                int iy = iy0 + sy, ix = ix0 + sx;
                bool ok = (sy < SY) && ((unsigned)iy < (unsigned)Hin) &&
                          ((unsigned)ix < (unsigned)Win);
                u16x4 v = {0, 0, 0, 0};
                if (ok) v = *reinterpret_cast<const u16x4*>(
                        &inh[(nbase + (size_t)iy * Win + ix) * 4]);
                *reinterpret_cast<u16x4*>(&Patch[0][j * 8]) = v;
                if (SIN) {
                    u16x4 w2 = {0, 0, 0, 0};
                    if (ok) w2 = *reinterpret_cast<const u16x4*>(
                            &inl[(nbase + (size_t)iy * Win + ix) * 4]);
                    *reinterpret_cast<u16x4*>(&Patch[1][j * 8]) = w2;
                }
            }
        }

        for (int p = 0; p < PPn; ++p) {
            // ---- stage A into alternating buffer ----
            {
                int kofs = (CT == 32) ? (p * Cin + cs * 32) : (p * 32);
                size_t widx = (size_t)(oc0 + sm) * Kp + kofs + soct * 8;
                int buf = step & 1;
                *reinterpret_cast<u16x8*>(&As[0][buf][stg]) =
                    *reinterpret_cast<const u16x8*>(&wh[widx]);
                if (SIN)
                    *reinterpret_cast<u16x8*>(&As[1][buf][stg]) =
                        *reinterpret_cast<const u16x8*>(&wl[widx]);
            }
            __syncthreads();
            const int buf = step & 1;
            // ---- A fragments ----
            bf16x8 ah[2], al[2];
            ah[0] = *reinterpret_cast<const bf16x8*>(&As[0][buf][aof]);
            ah[1] = *reinterpret_cast<const bf16x8*>(&As[0][buf][aof + 16 * 40]);
            if (SIN) {
                al[0] = *reinterpret_cast<const bf16x8*>(&As[1][buf][aof]);
                al[1] = *reinterpret_cast<const bf16x8*>(&As[1][buf][aof + 16 * 40]);
            }
            // ---- B fragments from patch ----
            bf16x8 bh[2], bl[2];
            if (CT == 32) {
                int ky = p / KS, kx = p - (p / KS) * KS;
                int kofs2 = ky * SX + kx;
#pragma unroll
                for (int ni = 0; ni < 2; ++ni) {
                    int pix = bbase[ni] + kofs2;
                    int bo = (pix * 64 + oct * 16) ^ (((pix >> 1) & 7) << 4);
                    bh[ni] = *reinterpret_cast<const bf16x8*>(&Patch[0][bo]);
                    if (SIN) bl[ni] = *reinterpret_cast<const bf16x8*>(&Patch[1][bo]);
                }
            } else {
#pragma unroll
                for (int ni = 0; ni < 2; ++ni) {
                    int s0_ = 8 * p + 2 * oct;
                    u16x4 parts_h[2], parts_l[2];
#pragma unroll
                    for (int e = 0; e < 2; ++e) {
                        int slot = s0_ + e;
                        int py = slot / KS, px = slot - (slot / KS) * KS;
                        int pix = bbase[ni] + py * SX + px;
                        parts_h[e] = *reinterpret_cast<const u16x4*>(&Patch[0][pix * 8]);
                        if (SIN)
                            parts_l[e] = *reinterpret_cast<const u16x4*>(&Patch[1][pix * 8]);
                    }
                    union { u16x4 q2[2]; bf16x8 f; } uh, ul;
                    uh.q2[0] = parts_h[0]; uh.q2[1] = parts_h[1];
                    bh[ni] = uh.f;
                    if (SIN) { ul.q2[0] = parts_l[0]; ul.q2[1] = parts_l[1]; bl[ni] = ul.f; }
                }
            }
            // ---- MFMA ----
#pragma unroll
            for (int mi = 0; mi < 2; ++mi)
#pragma unroll
                for (int ni = 0; ni < 2; ++ni)
                    acc[mi][ni] = __builtin_amdgcn_mfma_f32_16x16x32_bf16(
                        ah[mi], bh[ni], acc[mi][ni], 0, 0, 0);
            if (SIN) {
#pragma unroll
                for (int mi = 0; mi < 2; ++mi)
#pragma unroll
                    for (int ni = 0; ni < 2; ++ni) {
                        acc[mi][ni] = __builtin_amdgcn_mfma_f32_16x16x32_bf16(
                            ah[mi], bl[ni], acc[mi][ni], 0, 0, 0);
                        acc[mi][ni] = __builtin_amdgcn_mfma_f32_16x16x32_bf16(
                            al[mi], bh[ni], acc[mi][ni], 0, 0, 0);
                    }
            }
            ++step;
        }
    }

    // ---- epilogue ----
#pragma unroll
    for (int ni = 0; ni < 2; ++ni) {
        int c = nq + ni * 16 + cl;
        int dy = c / TX, dx = c - (c / TX) * TX;
        int oy = ty0 + dy, ox = tx0 + dx;
        if (oy >= Hout || ox >= Wout) continue;
        int pos = oy * Wout + ox;
        const int oc_b = oc0 + mq + oct * 4;
        if constexpr (MOUT == 2) {
#pragma unroll
            for (int mi = 0; mi < 2; ++mi) {
                int oc = oc_b + mi * 16;
#pragma unroll
                for (int r3 = 0; r3 < 4; ++r3) {
                    float v = acc[mi][ni][r3];
                    if (cbias) v += cbias[oc + r3];
                    v = fmaf(v, gam[oc + r3], bet[oc + r3]);
                    v = fmaxf(v, 0.f);
                    outf[((size_t)n * Cout + oc + r3) * HWout + pos] = v;
                }
            }
        } else {
#pragma unroll
            for (int mi = 0; mi < 2; ++mi) {
                int oc = oc_b + mi * 16;
                u16 hh[4], ll[4];
#pragma unroll
                for (int r3 = 0; r3 < 4; ++r3) {
                    float v = acc[mi][ni][r3];
                    if (cbias) v += cbias[oc + r3];
                    v = fmaf(v, gam[oc + r3], bet[oc + r3]);
                    v = fmaxf(v, 0.f);
                    u16 h = f2bf(v);
                    hh[r3] = h;
                    if (MOUT == 1) ll[r3] = f2bf(v - bf2f(h));
                }
                *reinterpret_cast<u16x4*>(&outh[((size_t)n * HWout + pos) * Cout + oc]) =
                    *reinterpret_cast<u16x4*>(hh);
                if constexpr (MOUT == 1)
                    *reinterpret_cast<u16x4*>(&outl[((size_t)n * HWout + pos) * Cout + oc]) =
                        *reinterpret_cast<u16x4*>(ll);
            }
        }
    }
}

// ---------------------------------------------------------------------------
// 2x2 maxpool stride 2 (fp32 NCHW)
// ---------------------------------------------------------------------------
__global__ void maxpool2(const float* __restrict__ in, float* __restrict__ out,
                         int NC, int H, int W) {
    int Ho = H >> 1, Wo = W >> 1;
    size_t idx = (size_t)blockIdx.x * blockDim.x + threadIdx.x;
    size_t total = (size_t)NC * Ho * Wo;
    if (idx >= total) return;
    int ox = idx % Wo;
    size_t t = idx / Wo;
    int oy = t % Ho;
    int nc = t / Ho;
    const float* p = in + ((size_t)nc * H + oy * 2) * W + ox * 2;
    out[idx] = fmaxf(fmaxf(p[0], p[1]), fmaxf(p[W], p[W + 1]));
}

// ---------------------------------------------------------------------------
// K-split linear, pass 1: partial[(c*Nn+n)*64+j] = X[n, cKc:(c+1)Kc].W[j,...]
// grid = nchunks*Nn blocks (c-major); each wave owns j = wv, wv+4, ...
// ---------------------------------------------------------------------------
__global__ __launch_bounds__(256) void lin_part(
    const float* __restrict__ X, const float* __restrict__ W,
    float* __restrict__ partial, int K, int Kc, int Ncols, int Nn) {
    int c = blockIdx.x / Nn;
    int n = blockIdx.x - c * Nn;
    int lane = threadIdx.x & 63, wv = threadIdx.x >> 6;
    const float4* x4 = reinterpret_cast<const float4*>(X + (size_t)n * K + (size_t)c * Kc);
    int K4 = Kc >> 2;
    for (int j = wv; j < Ncols; j += 4) {
        const float4* w4 =
            reinterpret_cast<const float4*>(W + (size_t)j * K + (size_t)c * Kc);
        float s = 0.f;
        for (int k = lane; k < K4; k += 64) {
            float4 a = x4[k], b = w4[k];
            s = fmaf(a.x, b.x, s);
            s = fmaf(a.y, b.y, s);
            s = fmaf(a.z, b.z, s);
            s = fmaf(a.w, b.w, s);
        }
#pragma unroll
        for (int off = 32; off > 0; off >>= 1) s += __shfl_down(s, off, 64);
        if (lane == 0) partial[((size_t)c * Nn + n) * 64 + j] = s;
    }
}

// pass 2: out[n*Ncols+j] = bias[j] + sum_c partial
__global__ void lin_reduce(const float* __restrict__ partial,
                           const float* __restrict__ bias, float* __restrict__ out,
                           int Ncols, int Nn, int nchunks) {
    int t = blockIdx.x * blockDim.x + threadIdx.x;
    if (t >= Nn * Ncols) return;
    int n = t / Ncols, j = t - n * Ncols;
    float s = bias[j];
    for (int c = 0; c < nchunks; ++c) s += partial[((size_t)c * Nn + n) * 64 + j];
    out[t] = s;
}

// ---------------------------------------------------------------------------
// rotation matrices + bias vectors from o[Nc,6]
// ---------------------------------------------------------------------------
__global__ void make_rot(const float* __restrict__ o6, float* __restrict__ R,
                         float* __restrict__ bv, int Nc) {
    int n = threadIdx.x;
    if (n >= Nc) return;
    const float PI = 3.14159265358979323846f;
    float a0 = o6[n * 6 + 0] * PI, a1 = o6[n * 6 + 1] * PI, a2 = o6[n * 6 + 2] * PI;
    float c0 = cosf(a0), c1 = cosf(a1), c2 = cosf(a2);
    float s0 = sinf(a0), s1 = sinf(a1), s2 = sinf(a2);
    float Rx[9] = {1, 0, 0, 0, c0, s0, 0, -s0, c0};
    float Ry[9] = {c1, 0, -s1, 0, 1, 0, s1, 0, c1};
    float Rz[9] = {c2, s2, 0, -s2, c2, 0, 0, 0, 1};
    float M[9], Rm[9];
#pragma unroll
    for (int i = 0; i < 3; ++i)
#pragma unroll
        for (int j = 0; j < 3; ++j) {
            float acc = 0.f;
#pragma unroll
            for (int k = 0; k < 3; ++k) acc = fmaf(Ry[i * 3 + k], Rz[k * 3 + j], acc);
            M[i * 3 + j] = acc;
        }
#pragma unroll
    for (int i = 0; i < 3; ++i)
#pragma unroll
        for (int j = 0; j < 3; ++j) {
            float acc = 0.f;
#pragma unroll
            for (int k = 0; k < 3; ++k) acc = fmaf(Rx[i * 3 + k], M[k * 3 + j], acc);
            Rm[i * 3 + j] = acc;
        }
    const float MINV = -3.602826f;
    float v0 = MINV - o6[n * 6 + 3];
    float v1 = MINV - o6[n * 6 + 4];
    float v2 = MINV - o6[n * 6 + 5];
#pragma unroll
    for (int i = 0; i < 3; ++i) {
        float sh = Rm[i * 3 + 0] * v0 + Rm[i * 3 + 1] * v1 + Rm[i * 3 + 2] * v2;
        bv[n * 3 + i] = 255.f * (sh - MINV) / 8.812765f;
        R[n * 9 + i * 3 + 0] = Rm[i * 3 + 0];
        R[n * 9 + i * 3 + 1] = Rm[i * 3 + 1];
        R[n * 9 + i * 3 + 2] = Rm[i * 3 + 2];
    }
}

// ---------------------------------------------------------------------------
// z = R.x + bias -> NHWC-C4 bf16
// ---------------------------------------------------------------------------
__global__ void rot_apply3(const float* __restrict__ X, const float* __restrict__ R,
                           const float* __restrict__ bv, u16* __restrict__ z,
                           int HW, size_t total) {
    size_t idx = (size_t)blockIdx.x * blockDim.x + threadIdx.x;
    if (idx >= total) return;
    int n = idx / HW;
    int p = idx - (size_t)n * HW;
    const float* xb = X + (size_t)n * 3 * HW + p;
    float x0 = xb[0], x1 = xb[HW], x2 = xb[(size_t)2 * HW];
    u16 o[4];
#pragma unroll
    for (int i = 0; i < 3; ++i) {
        float v = fmaf(R[n * 9 + i * 3 + 0], x0,
                  fmaf(R[n * 9 + i * 3 + 1], x1,
                  fmaf(R[n * 9 + i * 3 + 2], x2, bv[n * 3 + i])));
        o[i] = f2bf(v);
    }
    o[3] = 0;
    *reinterpret_cast<u16x4*>(&z[((size_t)n * HW + p) * 4]) = *reinterpret_cast<u16x4*>(o);
}

__global__ void copy_kernel(const float* __restrict__ a, float* __restrict__ o, size_t n) {
    size_t i = (size_t)blockIdx.x * blockDim.x + threadIdx.x;
    if (i < n) o[i] = a[i];
}
__global__ void max_kernel(const float* __restrict__ a, float* __restrict__ o, size_t n) {
    size_t i = (size_t)blockIdx.x * blockDim.x + threadIdx.x;
    if (i < n) o[i] = fmaxf(o[i], a[i]);
}

// ---------------------------------------------------------------------------
static inline int nblk(size_t total, int bs) { return (int)((total + bs - 1) / bs); }

extern "C" void kernel_launch(void* const* d_in, const int* in_sizes, int n_in,
                              void* d_out, int out_size, void* d_ws, size_t ws_size,
                              hipStream_t stream) {
    const float* x   = (const float*)d_in[0];
    const float* w1  = (const float*)d_in[1];
    const float* b1  = (const float*)d_in[2];
    const float* g1  = (const float*)d_in[3];
    const float* be1 = (const float*)d_in[4];
    const float* w2  = (const float*)d_in[5];
    const float* b2  = (const float*)d_in[6];
    const float* g2  = (const float*)d_in[7];
    const float* be2 = (const float*)d_in[8];
    const float* fw  = (const float*)d_in[9];
    const float* fb  = (const float*)d_in[10];
    const float* bw[5], *bg[5], *bb[5];
    for (int i = 0; i < 5; ++i) {
        bw[i] = (const float*)d_in[11 + 3 * i];
        bg[i] = (const float*)d_in[12 + 3 * i];
        bb[i] = (const float*)d_in[13 + 3 * i];
    }
    const float* lw = (const float*)d_in[26];
    const float* lb = (const float*)d_in[27];
    float* out = (float*)d_out;

    const int N = 32;
    const int BS = 256;

    const int bC[6] = {3, 64, 256, 512, 1024, 2048};
    const int bH[6] = {224, 112, 56, 28, 14, 7};
    const int K1p = 128;
    const int K2p = 3200;
    const int Kbp[5] = {64, 576, 2304, 4608, 9216};

    const size_t S_X = 150528;      // fp32 NCHW
    const size_t S_C4 = 200704;     // u16 NHWC-C4
    const size_t S_B1u = 1605632;   // u16 NHWC 112*112*128
    const size_t S_B2f = 401408;    // fp32 NCHW 128*56*56
    const size_t S_Pp = 100352;     // fp32
    const size_t per_sample_B = S_X * 4 + S_C4 * 2 * 3 + S_B1u * 2 * 2 +
                                S_B2f * 4 + S_Pp * 4;
    size_t wu = (size_t)128 * K1p * 2 + (size_t)128 * K2p * 2;
    for (int i = 0; i < 5; ++i) wu += (size_t)bC[i + 1] * Kbp[i];
    const size_t fixed_B = (size_t)N * S_Pp * 4 + 8192 + wu * 2 + 16384 * 4 + 64;

    int Nc = N;
    while (Nc > 1 && (size_t)Nc * per_sample_B + fixed_B > ws_size) Nc >>= 1;

    // ---- carve workspace ----
    char* cur = (char*)d_ws;
    auto alf = [&](size_t n) { float* p = (float*)cur; cur += n * sizeof(float); return p; };
    auto alu = [&](size_t n) { u16* p = (u16*)cur; cur += ((n + 7) & ~(size_t)7) * sizeof(u16); return p; };

    float* PM = alf((size_t)N * S_Pp);
    float* O6 = alf(256);
    float* Rm = alf(384);
    float* BV = alf(384);
    float* LP = alf(16384);          // linear partials [8][N][64]
    u16* w1h = alu((size_t)128 * K1p);
    u16* w1l = alu((size_t)128 * K1p);
    u16* w2h = alu((size_t)128 * K2p);
    u16* w2l = alu((size_t)128 * K2p);
    u16* wbh[5];
    for (int i = 0; i < 5; ++i) wbh[i] = alu((size_t)bC[i + 1] * Kbp[i]);
    float* X = alf((size_t)Nc * S_X);
    u16* Xh = alu((size_t)Nc * S_C4);
    u16* Xl = alu((size_t)Nc * S_C4);
    u16* Z16 = alu((size_t)Nc * S_C4);
    u16* B1h = alu((size_t)Nc * S_B1u);
    u16* B1l = alu((size_t)Nc * S_B1u);
    float* B2f = alf((size_t)Nc * S_B2f);
    float* Pp = alf((size_t)Nc * S_Pp);

    // ---- weight repacks ----
    repack_w4<<<nblk((size_t)128 * K1p, BS), BS, 0, stream>>>(w1, w1h, w1l, 128, 25, 32);
    repack_w32<<<nblk((size_t)128 * 128 * 25, BS), BS, 0, stream>>>(w2, w2h, w2l, 128, 128, 25);
    repack_w4<<<nblk((size_t)64 * Kbp[0], BS), BS, 0, stream>>>(bw[0], wbh[0], nullptr, 64, 9, 16);
    for (int i = 1; i < 5; ++i)
        repack_w32<<<nblk((size_t)bC[i + 1] * bC[i] * 9, BS), BS, 0, stream>>>(
            bw[i], wbh[i], nullptr, bC[i + 1], bC[i], 9);

    for (int m = 0; m < 2; ++m) {
        for (int c0 = 0; c0 < N; c0 += Nc) {
            const float* xc = x + (size_t)c0 * S_X * 2;
            size_t nNP = (size_t)Nc * 224 * 224;
            extract_person3<<<nblk(nNP, BS), BS, 0, stream>>>(xc, X, Xh, Xl, m, 224 * 224, nNP);

            // conv1: 3->128 5x5 s2 p2 (CT4 split, split-out NHWC), tiles 14x14
            {
                int Nt = Nc * 196;
                conv_mfma_p<5, 2, 4, 8, 8, true, 1><<<2 * Nt, 256, 0, stream>>>(
                    Xh, Xl, w1h, w1l, b1, g1, be1, B1h, B1l, nullptr,
                    Nc, 4, 224, 224, 128, 112, 112, K1p, Nt, 196, 14);
            }
            // conv2: 128->128 5x5 s2 p2 (CT32 split, fp32 NCHW out), tiles 7x7
            {
                int Nt = Nc * 49;
                conv_mfma_p<5, 2, 32, 8, 8, true, 2><<<2 * Nt, 256, 0, stream>>>(
                    B1h, B1l, w2h, w2l, b2, g2, be2, nullptr, nullptr, B2f,
                    Nc, 128, 112, 112, 128, 56, 56, K2p, Nt, 49, 7);
            }
            size_t nP = (size_t)Nc * S_Pp;
            maxpool2<<<nblk(nP, BS), BS, 0, stream>>>(B2f, Pp, Nc * 128, 56, 56);
            // fc: K-split linear (8 chunks) -> O6
            lin_part<<<8 * Nc, 256, 0, stream>>>(Pp, fw, LP, 100352, 12544, 6, Nc);
            lin_reduce<<<nblk(Nc * 6, 64), 64, 0, stream>>>(LP, fb, O6, 6, Nc, 8);
            make_rot<<<1, 64, 0, stream>>>(O6, Rm, BV, Nc);
            rot_apply3<<<nblk(nNP, BS), BS, 0, stream>>>(X, Rm, BV, Z16, 224 * 224, nNP);

            // backbone
            {
                // bw1: 3(4)->64, 224->112, CT4, tiles 14x14
                int Nt = Nc * 196;
                conv_mfma_p<3, 1, 4, 8, 8, false, 0><<<1 * Nt, 256, 0, stream>>>(
                    Z16, nullptr, wbh[0], nullptr, nullptr, bg[0], bb[0],
                    B1h, nullptr, nullptr,
                    Nc, 4, 224, 224, 64, 112, 112, Kbp[0], Nt, 196, 14);
            }
            {
                // bw2: 64->256, 112->56, tiles 7x7
                int Nt = Nc * 49;
                conv_mfma_p<3, 1, 32, 8, 8, false, 0><<<4 * Nt, 256, 0, stream>>>(
                    B1h, nullptr, wbh[1], nullptr, nullptr, bg[1], bb[1],
                    B1l, nullptr, nullptr,
                    Nc, 64, 112, 112, 256, 56, 56, Kbp[1], Nt, 49, 7);
            }
            {
                // bw3: 256->512, 56->28, TY4 TX16: tiles 7x2
                int Nt = Nc * 14;
                conv_mfma_p<3, 1, 32, 4, 16, false, 0><<<8 * Nt, 256, 0, stream>>>(
                    B1l, nullptr, wbh[2], nullptr, nullptr, bg[2], bb[2],
                    B1h, nullptr, nullptr,
                    Nc, 256, 56, 56, 512, 28, 28, Kbp[2], Nt, 14, 2);
            }
            {
                // bw4: 512->1024, 28->14, TY4 TX16: tiles 4x1
                int Nt = Nc * 4;
                conv_mfma_p<3, 1, 32, 4, 16, false, 0><<<16 * Nt, 256, 0, stream>>>(
                    B1h, nullptr, wbh[3], nullptr, nullptr, bg[3], bb[3],
                    B1l, nullptr, nullptr,
                    Nc, 512, 28, 28, 1024, 14, 14, Kbp[3], Nt, 4, 1);
            }
            {
                // bw5: 1024->2048, 14->7, tiles 1x1, fp32 NCHW out
                int Nt = Nc;
                conv_mfma_p<3, 1, 32, 8, 8, false, 2><<<32 * Nt, 256, 0, stream>>>(
                    B1l, nullptr, wbh[4], nullptr, nullptr, bg[4], bb[4],
                    nullptr, nullptr, Pp,
                    Nc, 1024, 14, 14, 2048, 7, 7, Kbp[4], Nt, 1, 1);
            }

            float* PMc = PM + (size_t)c0 * S_Pp;
            size_t nOut = (size_t)Nc * S_Pp;
            if (m == 0)
                copy_kernel<<<nblk(nOut, BS), BS, 0, stream>>>(Pp, PMc, nOut);
            else
                max_kernel<<<nblk(nOut, BS), BS, 0, stream>>>(Pp, PMc, nOut);
        }
    }

    // final linear: K-split (8 chunks) -> out
    lin_part<<<8 * N, 256, 0, stream>>>(PM, lw, LP, 100352, 12544, 60, N);
    lin_reduce<<<nblk(N * 60, 64), 64, 0, stream>>>(LP, lb, out, 60, N, 8);
}